// Round 1
// baseline (123.559 us; speedup 1.0000x reference)
//
#include <hip/hip_runtime.h>
#include <hip/hip_bf16.h>

#define H    4
#define HID  256
#define CDIM 512
#define NB   1024   // blocks in score pass

// ws layout (float offsets)
#define WS_W2   0                  // H*CDIM
#define WS_PRE  (H*CDIM)           // H
#define WS_GMAX (WS_PRE + H)       // H
#define WS_GINV (WS_GMAX + H)      // H
#define WS_BMAX (WS_GINV + H)      // H*NB
#define WS_BSUM (WS_BMAX + H*NB)   // H*NB

// Pass A: w2[h,c] = sum_d a2[h,d]*Ws[h,d,c];  pre[h] = pe.w1[h] + bs[h].(a1[h]+a2[h])
__global__ void __launch_bounds__(256) prep_kernel(
    const float* __restrict__ pe, const float* __restrict__ Ws,
    const float* __restrict__ bs, const float* __restrict__ as_,
    float* __restrict__ ws)
{
    int h = blockIdx.x;
    int t = threadIdx.x;                 // 0..255
    const float* W  = Ws + (size_t)h * HID * CDIM;
    const float* a1 = as_ + (size_t)h * 2 * HID;
    const float* a2 = a1 + HID;
    int c0 = t, c1 = t + 256;
    float w1a = 0.f, w2a = 0.f, w1b = 0.f, w2b = 0.f;
    for (int d = 0; d < HID; ++d) {
        float x0 = W[d * CDIM + c0];
        float x1 = W[d * CDIM + c1];
        float v1 = a1[d], v2 = a2[d];
        w1a = fmaf(v1, x0, w1a); w2a = fmaf(v2, x0, w2a);
        w1b = fmaf(v1, x1, w1b); w2b = fmaf(v2, x1, w2b);
    }
    ws[WS_W2 + h * CDIM + c0] = w2a;
    ws[WS_W2 + h * CDIM + c1] = w2b;
    // pre[h] = sum_c pe[c]*w1[h,c] + sum_d bs[h,d]*(a1[h,d]+a2[h,d])
    float contrib = w1a * pe[c0] + w1b * pe[c1];
    float b = bs[h * HID + t];
    contrib += b * (a1[t] + a2[t]);
    __shared__ float red[256];
    red[t] = contrib;
    __syncthreads();
    for (int s2 = 128; s2 > 0; s2 >>= 1) {
        if (t < s2) red[t] += red[t + s2];
        __syncthreads();
    }
    if (t == 0) ws[WS_PRE + h] = red[0];
}

// Pass B: wave-per-row. e[h,n] = leaky(pre[h] + code[n,:].w2[h,:]) -> d_out,
// online (max,sum) per wave -> block combine -> ws partials.
__global__ void __launch_bounds__(256) score_kernel(
    const float* __restrict__ codes, const float* __restrict__ ws_in,
    float* __restrict__ e_out, float* __restrict__ ws_out, int n_codes)
{
    const int lane = threadIdx.x & 63;
    const int wid  = threadIdx.x >> 6;        // 0..3
    const int gw   = blockIdx.x * 4 + wid;    // global wave id
    const int Wtot = gridDim.x * 4;

    // w2 fragments: lane covers cols [4*lane,4*lane+4) and [256+4*lane, +4)
    float4 w2a[H], w2b[H];
    float pre[H];
#pragma unroll
    for (int h = 0; h < H; ++h) {
        w2a[h] = *(const float4*)&ws_in[WS_W2 + h * CDIM + 4 * lane];
        w2b[h] = *(const float4*)&ws_in[WS_W2 + h * CDIM + 256 + 4 * lane];
        pre[h] = ws_in[WS_PRE + h];
    }

    float m0 = -1e30f, m1 = -1e30f, m2 = -1e30f, m3 = -1e30f;
    float s0 = 0.f, s1 = 0.f, s2 = 0.f, s3 = 0.f;

    for (int n = gw; n < n_codes; n += Wtot) {
        const float4* r = (const float4*)(codes + (size_t)n * CDIM);
        float4 xa = r[lane];
        float4 xb = r[64 + lane];
        float e[H];
#pragma unroll
        for (int h = 0; h < H; ++h) {
            float acc = xa.x * w2a[h].x + xa.y * w2a[h].y +
                        xa.z * w2a[h].z + xa.w * w2a[h].w +
                        xb.x * w2b[h].x + xb.y * w2b[h].y +
                        xb.z * w2b[h].z + xb.w * w2b[h].w;
            // 64-lane butterfly sum
            for (int msk = 32; msk; msk >>= 1) acc += __shfl_xor(acc, msk, 64);
            float raw = pre[h] + acc;
            e[h] = raw >= 0.f ? raw : 0.2f * raw;
        }
        // online softmax state (identical in all lanes)
        {
            float mm;
            mm = fmaxf(m0, e[0]); s0 = s0 * __expf(m0 - mm) + __expf(e[0] - mm); m0 = mm;
            mm = fmaxf(m1, e[1]); s1 = s1 * __expf(m1 - mm) + __expf(e[1] - mm); m1 = mm;
            mm = fmaxf(m2, e[2]); s2 = s2 * __expf(m2 - mm) + __expf(e[2] - mm); m2 = mm;
            mm = fmaxf(m3, e[3]); s3 = s3 * __expf(m3 - mm) + __expf(e[3] - mm); m3 = mm;
        }
        if (lane < H) {
            float ev = lane == 0 ? e[0] : lane == 1 ? e[1] : lane == 2 ? e[2] : e[3];
            e_out[(size_t)lane * n_codes + n] = ev;
        }
    }

    // block combine: 4 waves -> one (max,sum) per head
    __shared__ float lm[4][H], ls[4][H];
    if (lane == 0) {
        lm[wid][0] = m0; lm[wid][1] = m1; lm[wid][2] = m2; lm[wid][3] = m3;
        ls[wid][0] = s0; ls[wid][1] = s1; ls[wid][2] = s2; ls[wid][3] = s3;
    }
    __syncthreads();
    if (threadIdx.x == 0) {
#pragma unroll
        for (int h = 0; h < H; ++h) {
            float M = -1e30f, S = 0.f;
#pragma unroll
            for (int w = 0; w < 4; ++w) {
                float mm = fmaxf(M, lm[w][h]);
                S = S * __expf(M - mm) + ls[w][h] * __expf(lm[w][h] - mm);
                M = mm;
            }
            ws_out[WS_BMAX + h * NB + blockIdx.x] = M;
            ws_out[WS_BSUM + h * NB + blockIdx.x] = S;
        }
    }
}

// Pass C: one block, wave w reduces head w over NB partials.
__global__ void __launch_bounds__(256) sreduce_kernel(float* __restrict__ ws)
{
    int lane = threadIdx.x & 63;
    int h    = threadIdx.x >> 6;  // 0..3
    float M = -1e30f, S = 0.f;
    for (int i = lane; i < NB; i += 64) {
        float bm = ws[WS_BMAX + h * NB + i];
        float bs_ = ws[WS_BSUM + h * NB + i];
        float mm = fmaxf(M, bm);
        S = S * __expf(M - mm) + bs_ * __expf(bm - mm);
        M = mm;
    }
    for (int msk = 32; msk; msk >>= 1) {
        float M2 = __shfl_xor(M, msk, 64);
        float S2 = __shfl_xor(S, msk, 64);
        float mm = fmaxf(M, M2);
        S = S * __expf(M - mm) + S2 * __expf(M2 - mm);
        M = mm;
    }
    if (lane == 0) { ws[WS_GMAX + h] = M; ws[WS_GINV + h] = 1.f / S; }
}

// Pass D: alpha = exp(e - gmax[h]) * inv[h], float4 over the 3.2 MB e matrix.
__global__ void __launch_bounds__(256) norm_kernel(
    float* __restrict__ e, const float* __restrict__ ws, int n_codes)
{
    int i = blockIdx.x * blockDim.x + threadIdx.x;    // float4 index
    int perh = n_codes >> 2;
    int tot = H * perh;
    if (i >= tot) return;
    int h = i / perh;
    float gm = ws[WS_GMAX + h], gi = ws[WS_GINV + h];
    float4 v = ((float4*)e)[i];
    v.x = __expf(v.x - gm) * gi;
    v.y = __expf(v.y - gm) * gi;
    v.z = __expf(v.z - gm) * gi;
    v.w = __expf(v.w - gm) * gi;
    ((float4*)e)[i] = v;
}

extern "C" void kernel_launch(void* const* d_in, const int* in_sizes, int n_in,
                              void* d_out, int out_size, void* d_ws, size_t ws_size,
                              hipStream_t stream)
{
    const float* pe    = (const float*)d_in[0];   // (1,512)
    const float* codes = (const float*)d_in[1];   // (n,512)
    const float* Ws    = (const float*)d_in[2];   // (4,256,512)
    const float* bs    = (const float*)d_in[3];   // (4,256)
    const float* as_   = (const float*)d_in[4];   // (4,512)
    float* out = (float*)d_out;                   // (4,n)
    float* ws  = (float*)d_ws;
    int n_codes = in_sizes[1] / CDIM;

    prep_kernel<<<H, 256, 0, stream>>>(pe, Ws, bs, as_, ws);
    score_kernel<<<NB, 256, 0, stream>>>(codes, ws, out, ws, n_codes);
    sreduce_kernel<<<1, 256, 0, stream>>>(ws);
    int tot4 = (H * n_codes) / 4;
    norm_kernel<<<(tot4 + 255) / 256, 256, 0, stream>>>(out, ws, n_codes);
}

// Round 2
// 101.985 us; speedup vs baseline: 1.2115x; 1.2115x over previous
//
#include <hip/hip_runtime.h>
#include <hip/hip_bf16.h>

#define H     4
#define HID   256
#define CDIM  512
#define NCH   16              // d-chunks in prepA
#define DPER  (HID / NCH)     // 16 rows per chunk
#define NB    2048            // blocks in score pass

// ws layout (float offsets)
#define WS_P1   0                        // H*NCH*CDIM  w1 partials
#define WS_P2   (WS_P1 + H * NCH * CDIM) // H*NCH*CDIM  w2 partials
#define WS_W2   (WS_P2 + H * NCH * CDIM) // H*CDIM
#define WS_PRE  (WS_W2 + H * CDIM)       // H
#define WS_GMAX (WS_PRE + H)             // H
#define WS_GINV (WS_GMAX + H)            // H
#define WS_BMS  (WS_GINV + H)            // H*NB*2 (max,sum interleaved)

// Pass A1: partial w1/w2 over d-chunks. 64 blocks, each reads 32KB contiguous.
__global__ void __launch_bounds__(256) prepA_kernel(
    const float* __restrict__ Ws, const float* __restrict__ as_,
    float* __restrict__ ws)
{
    int h = blockIdx.x >> 4, chunk = blockIdx.x & (NCH - 1);
    int t = threadIdx.x;
    const float* W  = Ws + ((size_t)h * HID + chunk * DPER) * CDIM;
    const float* a1 = as_ + (size_t)h * 2 * HID + chunk * DPER;
    const float* a2 = a1 + HID;
    int c0 = t, c1 = t + 256;
    float w1a = 0.f, w1b = 0.f, w2a = 0.f, w2b = 0.f;
#pragma unroll
    for (int d = 0; d < DPER; ++d) {
        float x0 = W[d * CDIM + c0], x1 = W[d * CDIM + c1];
        float v1 = a1[d], v2 = a2[d];
        w1a = fmaf(v1, x0, w1a); w2a = fmaf(v2, x0, w2a);
        w1b = fmaf(v1, x1, w1b); w2b = fmaf(v2, x1, w2b);
    }
    size_t base = (size_t)(h * NCH + chunk) * CDIM;
    ws[WS_P1 + base + c0] = w1a; ws[WS_P1 + base + c1] = w1b;
    ws[WS_P2 + base + c0] = w2a; ws[WS_P2 + base + c1] = w2b;
}

// Pass A2: reduce chunk partials -> w2[h,c]; pre[h] = pe.w1 + bs.(a1+a2)
__global__ void __launch_bounds__(256) prepB_kernel(
    const float* __restrict__ pe, const float* __restrict__ bs,
    const float* __restrict__ as_, float* __restrict__ ws)
{
    int h = blockIdx.x;
    int t = threadIdx.x;
    int c0 = t, c1 = t + 256;
    float w1a = 0.f, w1b = 0.f, w2a = 0.f, w2b = 0.f;
#pragma unroll
    for (int k = 0; k < NCH; ++k) {
        size_t base = (size_t)(h * NCH + k) * CDIM;
        w1a += ws[WS_P1 + base + c0]; w1b += ws[WS_P1 + base + c1];
        w2a += ws[WS_P2 + base + c0]; w2b += ws[WS_P2 + base + c1];
    }
    ws[WS_W2 + h * CDIM + c0] = w2a;
    ws[WS_W2 + h * CDIM + c1] = w2b;
    const float* a1 = as_ + (size_t)h * 2 * HID;
    const float* a2 = a1 + HID;
    float contrib = w1a * pe[c0] + w1b * pe[c1];
    contrib += bs[h * HID + t] * (a1[t] + a2[t]);
    __shared__ float red[256];
    red[t] = contrib;
    __syncthreads();
    for (int s2 = 128; s2 > 0; s2 >>= 1) {
        if (t < s2) red[t] += red[t + s2];
        __syncthreads();
    }
    if (t == 0) ws[WS_PRE + h] = red[0];
}

// Pass B: wave-per-row-pair. Head-distributed reduction: butterfly 1,2 on
// 4 head accs, select by lane&3, shared butterfly 4,8,16,32. Each lane
// tracks online (m,s) for head lane&3 only -> 3 exps per 2 rows.
__global__ void __launch_bounds__(256) score_kernel(
    const float* __restrict__ codes, const float* __restrict__ ws_in,
    float* __restrict__ e_out, float* __restrict__ ws_out, int n_codes)
{
    const int lane = threadIdx.x & 63;
    const int wid  = threadIdx.x >> 6;
    const int gw   = blockIdx.x * 4 + wid;
    const int Wtot = gridDim.x * 4;

    float4 w2a[H], w2b[H];
#pragma unroll
    for (int h = 0; h < H; ++h) {
        w2a[h] = *(const float4*)&ws_in[WS_W2 + h * CDIM + 4 * lane];
        w2b[h] = *(const float4*)&ws_in[WS_W2 + h * CDIM + 256 + 4 * lane];
    }
    const bool b0 = lane & 1, b1 = lane & 2;
    // this lane's head = lane & 3
    float mypre;
    {
        float p0 = ws_in[WS_PRE + 0], p1 = ws_in[WS_PRE + 1];
        float p2 = ws_in[WS_PRE + 2], p3 = ws_in[WS_PRE + 3];
        float t01 = b0 ? p1 : p0, t23 = b0 ? p3 : p2;
        mypre = b1 ? t23 : t01;
    }

    float m = -1e30f, s = 0.f;
    const int npairs = n_codes >> 1;

    for (int p = gw; p < npairs; p += Wtot) {
        const int n0 = 2 * p;
        const float4* r0 = (const float4*)(codes + (size_t)n0 * CDIM);
        const float4* r1 = (const float4*)(codes + (size_t)(n0 + 1) * CDIM);
        float4 xa0 = r0[lane], xb0 = r0[64 + lane];
        float4 xa1 = r1[lane], xb1 = r1[64 + lane];

        float A0[H], A1[H];
#pragma unroll
        for (int h = 0; h < H; ++h) {
            A0[h] = xa0.x * w2a[h].x + xa0.y * w2a[h].y +
                    xa0.z * w2a[h].z + xa0.w * w2a[h].w +
                    xb0.x * w2b[h].x + xb0.y * w2b[h].y +
                    xb0.z * w2b[h].z + xb0.w * w2b[h].w;
            A1[h] = xa1.x * w2a[h].x + xa1.y * w2a[h].y +
                    xa1.z * w2a[h].z + xa1.w * w2a[h].w +
                    xb1.x * w2b[h].x + xb1.y * w2b[h].y +
                    xb1.z * w2b[h].z + xb1.w * w2b[h].w;
        }
        // butterfly masks 1,2 on all 8 accs
#pragma unroll
        for (int h = 0; h < H; ++h) {
            A0[h] += __shfl_xor(A0[h], 1, 64);
            A0[h] += __shfl_xor(A0[h], 2, 64);
            A1[h] += __shfl_xor(A1[h], 1, 64);
            A1[h] += __shfl_xor(A1[h], 2, 64);
        }
        // select this lane's head
        float t01 = b0 ? A0[1] : A0[0], t23 = b0 ? A0[3] : A0[2];
        float v0 = b1 ? t23 : t01;
        t01 = b0 ? A1[1] : A1[0]; t23 = b0 ? A1[3] : A1[2];
        float v1 = b1 ? t23 : t01;
        // shared butterfly over remaining lanes
#pragma unroll
        for (int msk = 4; msk <= 32; msk <<= 1) {
            v0 += __shfl_xor(v0, msk, 64);
            v1 += __shfl_xor(v1, msk, 64);
        }
        float e0 = mypre + v0; e0 = e0 >= 0.f ? e0 : 0.2f * e0;
        float e1 = mypre + v1; e1 = e1 >= 0.f ? e1 : 0.2f * e1;
        // online (m,s) for this lane's head
        float mm = fmaxf(m, fmaxf(e0, e1));
        s = s * __expf(m - mm) + __expf(e0 - mm) + __expf(e1 - mm);
        m = mm;
        if (lane < H) {
            float2 ev = make_float2(e0, e1);
            *(float2*)&e_out[(size_t)lane * n_codes + n0] = ev;
        }
    }
    // odd tail (not hit for n=200000, kept for generality)
    if ((n_codes & 1) && gw == 0) {
        const int n0 = n_codes - 1;
        const float4* r0 = (const float4*)(codes + (size_t)n0 * CDIM);
        float4 xa0 = r0[lane], xb0 = r0[64 + lane];
        float A0[H];
#pragma unroll
        for (int h = 0; h < H; ++h) {
            A0[h] = xa0.x * w2a[h].x + xa0.y * w2a[h].y +
                    xa0.z * w2a[h].z + xa0.w * w2a[h].w +
                    xb0.x * w2b[h].x + xb0.y * w2b[h].y +
                    xb0.z * w2b[h].z + xb0.w * w2b[h].w;
            A0[h] += __shfl_xor(A0[h], 1, 64);
            A0[h] += __shfl_xor(A0[h], 2, 64);
        }
        float t01 = b0 ? A0[1] : A0[0], t23 = b0 ? A0[3] : A0[2];
        float v0 = b1 ? t23 : t01;
#pragma unroll
        for (int msk = 4; msk <= 32; msk <<= 1) v0 += __shfl_xor(v0, msk, 64);
        float e0 = mypre + v0; e0 = e0 >= 0.f ? e0 : 0.2f * e0;
        float mm = fmaxf(m, e0);
        s = s * __expf(m - mm) + __expf(e0 - mm);
        m = mm;
        if (lane < H) e_out[(size_t)lane * n_codes + n0] = e0;
    }

    // block combine: lane h of each wave holds head h state
    __shared__ float lm[4][H], ls[4][H];
    if (lane < H) { lm[wid][lane] = m; ls[wid][lane] = s; }
    __syncthreads();
    if (threadIdx.x < H) {
        int h = threadIdx.x;
        float M = -1e30f, S = 0.f;
#pragma unroll
        for (int w = 0; w < 4; ++w) {
            float mm = fmaxf(M, lm[w][h]);
            S = S * __expf(M - mm) + ls[w][h] * __expf(lm[w][h] - mm);
            M = mm;
        }
        float2 v = make_float2(M, S);
        *(float2*)&ws_out[WS_BMS + (size_t)(h * NB + blockIdx.x) * 2] = v;
    }
}

// Pass C: one block, wave h reduces head h over NB (max,sum) partials.
__global__ void __launch_bounds__(256) sreduce_kernel(float* __restrict__ ws)
{
    int lane = threadIdx.x & 63;
    int h    = threadIdx.x >> 6;
    float M = -1e30f, S = 0.f;
    for (int i = lane; i < NB; i += 64) {
        float2 v = *(const float2*)&ws[WS_BMS + (size_t)(h * NB + i) * 2];
        float mm = fmaxf(M, v.x);
        S = S * __expf(M - mm) + v.y * __expf(v.x - mm);
        M = mm;
    }
    for (int msk = 32; msk; msk >>= 1) {
        float M2 = __shfl_xor(M, msk, 64);
        float S2 = __shfl_xor(S, msk, 64);
        float mm = fmaxf(M, M2);
        S = S * __expf(M - mm) + S2 * __expf(M2 - mm);
        M = mm;
    }
    if (lane == 0) { ws[WS_GMAX + h] = M; ws[WS_GINV + h] = 1.f / S; }
}

// Pass D: alpha = exp(e - gmax[h]) * inv[h]
__global__ void __launch_bounds__(256) norm_kernel(
    float* __restrict__ e, const float* __restrict__ ws, int n_codes)
{
    int i = blockIdx.x * blockDim.x + threadIdx.x;
    int perh = n_codes >> 2;
    int tot = H * perh;
    if (i >= tot) return;
    int h = i / perh;
    float gm = ws[WS_GMAX + h], gi = ws[WS_GINV + h];
    float4 v = ((float4*)e)[i];
    v.x = __expf(v.x - gm) * gi;
    v.y = __expf(v.y - gm) * gi;
    v.z = __expf(v.z - gm) * gi;
    v.w = __expf(v.w - gm) * gi;
    ((float4*)e)[i] = v;
}

extern "C" void kernel_launch(void* const* d_in, const int* in_sizes, int n_in,
                              void* d_out, int out_size, void* d_ws, size_t ws_size,
                              hipStream_t stream)
{
    const float* pe    = (const float*)d_in[0];   // (1,512)
    const float* codes = (const float*)d_in[1];   // (n,512)
    const float* Ws    = (const float*)d_in[2];   // (4,256,512)
    const float* bs    = (const float*)d_in[3];   // (4,256)
    const float* as_   = (const float*)d_in[4];   // (4,512)
    float* out = (float*)d_out;                   // (4,n)
    float* ws  = (float*)d_ws;
    int n_codes = in_sizes[1] / CDIM;

    prepA_kernel<<<H * NCH, 256, 0, stream>>>(Ws, as_, ws);
    prepB_kernel<<<H, 256, 0, stream>>>(pe, bs, as_, ws);
    score_kernel<<<NB, 256, 0, stream>>>(codes, ws, out, ws, n_codes);
    sreduce_kernel<<<1, 256, 0, stream>>>(ws);
    int tot4 = (H * n_codes) / 4;
    norm_kernel<<<(tot4 + 255) / 256, 256, 0, stream>>>(out, ws, n_codes);
}

// Round 4
// 98.410 us; speedup vs baseline: 1.2556x; 1.0363x over previous
//
#include <hip/hip_runtime.h>
#include <hip/hip_bf16.h>

#define H     4
#define HID   256
#define CDIM  512
#define NCH   32              // d-chunks in prepA
#define DPER  (HID / NCH)     // 8 rows per chunk
#define NB    2048            // blocks in score pass

typedef float f32x4 __attribute__((ext_vector_type(4)));

// ws layout (float offsets)
#define WS_P1   0                        // H*NCH*CDIM  w1 partials
#define WS_P2   (WS_P1 + H * NCH * CDIM) // H*NCH*CDIM  w2 partials
#define WS_W2   (WS_P2 + H * NCH * CDIM) // H*CDIM
#define WS_PRE  (WS_W2 + H * CDIM)       // H
#define WS_GMAX (WS_PRE + H)             // H
#define WS_GINV (WS_GMAX + H)            // H
#define WS_BMS  (WS_GINV + H)            // H*NB*2 (max,sum interleaved)

// Pass A1: partial w1/w2 over d-chunks. 128 blocks, each reads 16KB contiguous.
__global__ void __launch_bounds__(256) prepA_kernel(
    const float* __restrict__ Ws, const float* __restrict__ as_,
    float* __restrict__ ws)
{
    int h = blockIdx.x >> 5, chunk = blockIdx.x & (NCH - 1);
    int t = threadIdx.x;
    const float* W  = Ws + ((size_t)h * HID + chunk * DPER) * CDIM;
    const float* a1 = as_ + (size_t)h * 2 * HID + chunk * DPER;
    const float* a2 = a1 + HID;
    int c0 = t, c1 = t + 256;
    float w1a = 0.f, w1b = 0.f, w2a = 0.f, w2b = 0.f;
#pragma unroll
    for (int d = 0; d < DPER; ++d) {
        float x0 = W[d * CDIM + c0], x1 = W[d * CDIM + c1];
        float v1 = a1[d], v2 = a2[d];
        w1a = fmaf(v1, x0, w1a); w2a = fmaf(v2, x0, w2a);
        w1b = fmaf(v1, x1, w1b); w2b = fmaf(v2, x1, w2b);
    }
    size_t base = (size_t)(h * NCH + chunk) * CDIM;
    ws[WS_P1 + base + c0] = w1a; ws[WS_P1 + base + c1] = w1b;
    ws[WS_P2 + base + c0] = w2a; ws[WS_P2 + base + c1] = w2b;
}

// Pass A2: reduce chunk partials -> w2[h,c]; pre[h] = pe.w1 + bs.(a1+a2)
__global__ void __launch_bounds__(256) prepB_kernel(
    const float* __restrict__ pe, const float* __restrict__ bs,
    const float* __restrict__ as_, float* __restrict__ ws)
{
    int h = blockIdx.x;
    int t = threadIdx.x;
    int c0 = t, c1 = t + 256;
    float w1a = 0.f, w1b = 0.f, w2a = 0.f, w2b = 0.f;
#pragma unroll
    for (int k = 0; k < NCH; ++k) {
        size_t base = (size_t)(h * NCH + k) * CDIM;
        w1a += ws[WS_P1 + base + c0]; w1b += ws[WS_P1 + base + c1];
        w2a += ws[WS_P2 + base + c0]; w2b += ws[WS_P2 + base + c1];
    }
    ws[WS_W2 + h * CDIM + c0] = w2a;
    ws[WS_W2 + h * CDIM + c1] = w2b;
    const float* a1 = as_ + (size_t)h * 2 * HID;
    const float* a2 = a1 + HID;
    float contrib = w1a * pe[c0] + w1b * pe[c1];
    contrib += bs[h * HID + t] * (a1[t] + a2[t]);
    __shared__ float red[256];
    red[t] = contrib;
    __syncthreads();
    for (int s2 = 128; s2 > 0; s2 >>= 1) {
        if (t < s2) red[t] += red[t + s2];
        __syncthreads();
    }
    if (t == 0) ws[WS_PRE + h] = red[0];
}

// Pass B: wave-per-row-pair, blocked contiguous ranges, NT loads.
// Full transpose-reduction: masks 1,2 on 8 accs -> head select -> mask 4 ->
// row select -> masks 8,16,32. 21 shfl + 1 online update (2 exp) per 2 rows.
// Lane ends with e for (head=lane&3, row-slot=(lane>>2)&1), 8x replicated.
__global__ void __launch_bounds__(256) score_kernel(
    const float* __restrict__ codes, const float* __restrict__ ws_in,
    float* __restrict__ e_out, float* __restrict__ ws_out, int n_codes)
{
    const int lane = threadIdx.x & 63;
    const int wid  = threadIdx.x >> 6;
    const int gw   = blockIdx.x * 4 + wid;
    const long long Wtot = (long long)gridDim.x * 4;

    f32x4 w2a[H], w2b[H];
#pragma unroll
    for (int h = 0; h < H; ++h) {
        w2a[h] = *(const f32x4*)&ws_in[WS_W2 + h * CDIM + 4 * lane];
        w2b[h] = *(const f32x4*)&ws_in[WS_W2 + h * CDIM + 256 + 4 * lane];
    }
    const int  hsel = lane & 3;
    const bool b0 = lane & 1, b1 = lane & 2, b2 = lane & 4;
    const float mypre = ws_in[WS_PRE + hsel];

    const long long npairs = (long long)n_codes >> 1;
    const long long ps = (long long)gw * npairs / Wtot;
    const long long pe_ = ((long long)gw + 1) * npairs / Wtot;

    float m = -1e30f, s = 0.f;

    for (long long p = ps; p < pe_; ++p) {
        const f32x4* r = (const f32x4*)(codes + ((size_t)p << 1) * CDIM);
        f32x4 xa0 = __builtin_nontemporal_load(&r[lane]);
        f32x4 xb0 = __builtin_nontemporal_load(&r[64 + lane]);
        f32x4 xa1 = __builtin_nontemporal_load(&r[128 + lane]);
        f32x4 xb1 = __builtin_nontemporal_load(&r[192 + lane]);

        float A0[H], A1[H];
#pragma unroll
        for (int h = 0; h < H; ++h) {
            A0[h] = xa0.x * w2a[h].x + xa0.y * w2a[h].y +
                    xa0.z * w2a[h].z + xa0.w * w2a[h].w +
                    xb0.x * w2b[h].x + xb0.y * w2b[h].y +
                    xb0.z * w2b[h].z + xb0.w * w2b[h].w;
            A1[h] = xa1.x * w2a[h].x + xa1.y * w2a[h].y +
                    xa1.z * w2a[h].z + xa1.w * w2a[h].w +
                    xb1.x * w2b[h].x + xb1.y * w2b[h].y +
                    xb1.z * w2b[h].z + xb1.w * w2b[h].w;
        }
#pragma unroll
        for (int h = 0; h < H; ++h) {
            A0[h] += __shfl_xor(A0[h], 1, 64);
            A0[h] += __shfl_xor(A0[h], 2, 64);
            A1[h] += __shfl_xor(A1[h], 1, 64);
            A1[h] += __shfl_xor(A1[h], 2, 64);
        }
        float t01 = b0 ? A0[1] : A0[0], t23 = b0 ? A0[3] : A0[2];
        float B0 = b1 ? t23 : t01;
        t01 = b0 ? A1[1] : A1[0]; t23 = b0 ? A1[3] : A1[2];
        float B1 = b1 ? t23 : t01;
        B0 += __shfl_xor(B0, 4, 64);
        B1 += __shfl_xor(B1, 4, 64);
        float C = b2 ? B1 : B0;
        C += __shfl_xor(C, 8, 64);
        C += __shfl_xor(C, 16, 64);
        C += __shfl_xor(C, 32, 64);

        float e = mypre + C;
        e = e >= 0.f ? e : 0.2f * e;
        float mm = fmaxf(m, e);
        s = s * __expf(m - mm) + __expf(e - mm);
        m = mm;
        if (!(lane & 56)) {   // lanes 0..7: (head 0..3) x (row-slot 0..1)
            e_out[(size_t)hsel * n_codes + ((size_t)p << 1) + (b2 ? 1 : 0)] = e;
        }
    }

    // odd global tail row (n_codes even here; kept for generality)
    if ((n_codes & 1) && gw == Wtot - 1) {
        const int n0 = n_codes - 1;
        const f32x4* r = (const f32x4*)(codes + (size_t)n0 * CDIM);
        f32x4 xa = __builtin_nontemporal_load(&r[lane]);
        f32x4 xb = __builtin_nontemporal_load(&r[64 + lane]);
        float A[H];
#pragma unroll
        for (int h = 0; h < H; ++h) {
            A[h] = xa.x * w2a[h].x + xa.y * w2a[h].y +
                   xa.z * w2a[h].z + xa.w * w2a[h].w +
                   xb.x * w2b[h].x + xb.y * w2b[h].y +
                   xb.z * w2b[h].z + xb.w * w2b[h].w;
            A[h] += __shfl_xor(A[h], 1, 64);
            A[h] += __shfl_xor(A[h], 2, 64);
        }
        float t01 = b0 ? A[1] : A[0], t23 = b0 ? A[3] : A[2];
        float v = b1 ? t23 : t01;
#pragma unroll
        for (int msk = 4; msk <= 32; msk <<= 1) v += __shfl_xor(v, msk, 64);
        float e = mypre + v;
        e = e >= 0.f ? e : 0.2f * e;
        if (!b2) {  // only row-slot-0 lanes absorb it (avoid double count)
            float mm = fmaxf(m, e);
            s = s * __expf(m - mm) + __expf(e - mm);
            m = mm;
        }
        if (lane < H) e_out[(size_t)hsel * n_codes + n0] = e;
    }

    // merge row-slots (bit 2 only; bits 3..5 are identical replicas)
    {
        float M2 = __shfl_xor(m, 4, 64);
        float S2 = __shfl_xor(s, 4, 64);
        float mm = fmaxf(m, M2);
        s = s * __expf(m - mm) + S2 * __expf(M2 - mm);
        m = mm;
    }

    __shared__ float lm[4][H], ls[4][H];
    if (lane < H) { lm[wid][lane] = m; ls[wid][lane] = s; }
    __syncthreads();
    if (threadIdx.x < H) {
        int h = threadIdx.x;
        float M = -1e30f, S = 0.f;
#pragma unroll
        for (int w = 0; w < 4; ++w) {
            float mm = fmaxf(M, lm[w][h]);
            S = S * __expf(M - mm) + ls[w][h] * __expf(lm[w][h] - mm);
            M = mm;
        }
        float2 v = make_float2(M, S);
        *(float2*)&ws_out[WS_BMS + (size_t)(h * NB + blockIdx.x) * 2] = v;
    }
}

// Pass C: one block, wave h reduces head h over NB (max,sum) partials.
__global__ void __launch_bounds__(256) sreduce_kernel(float* __restrict__ ws)
{
    int lane = threadIdx.x & 63;
    int h    = threadIdx.x >> 6;
    float M = -1e30f, S = 0.f;
    for (int i = lane; i < NB; i += 64) {
        float2 v = *(const float2*)&ws[WS_BMS + (size_t)(h * NB + i) * 2];
        float mm = fmaxf(M, v.x);
        S = S * __expf(M - mm) + v.y * __expf(v.x - mm);
        M = mm;
    }
    for (int msk = 32; msk; msk >>= 1) {
        float M2 = __shfl_xor(M, msk, 64);
        float S2 = __shfl_xor(S, msk, 64);
        float mm = fmaxf(M, M2);
        S = S * __expf(M - mm) + S2 * __expf(M2 - mm);
        M = mm;
    }
    if (lane == 0) { ws[WS_GMAX + h] = M; ws[WS_GINV + h] = 1.f / S; }
}

// Pass D: alpha = exp(e - gmax[h]) * inv[h]
__global__ void __launch_bounds__(256) norm_kernel(
    float* __restrict__ e, const float* __restrict__ ws, int n_codes)
{
    int i = blockIdx.x * blockDim.x + threadIdx.x;
    int perh = n_codes >> 2;
    int tot = H * perh;
    if (i >= tot) return;
    int h = i / perh;
    float gm = ws[WS_GMAX + h], gi = ws[WS_GINV + h];
    float4 v = ((float4*)e)[i];
    v.x = __expf(v.x - gm) * gi;
    v.y = __expf(v.y - gm) * gi;
    v.z = __expf(v.z - gm) * gi;
    v.w = __expf(v.w - gm) * gi;
    ((float4*)e)[i] = v;
}

extern "C" void kernel_launch(void* const* d_in, const int* in_sizes, int n_in,
                              void* d_out, int out_size, void* d_ws, size_t ws_size,
                              hipStream_t stream)
{
    const float* pe    = (const float*)d_in[0];   // (1,512)
    const float* codes = (const float*)d_in[1];   // (n,512)
    const float* Ws    = (const float*)d_in[2];   // (4,256,512)
    const float* bs    = (const float*)d_in[3];   // (4,256)
    const float* as_   = (const float*)d_in[4];   // (4,512)
    float* out = (float*)d_out;                   // (4,n)
    float* ws  = (float*)d_ws;
    int n_codes = in_sizes[1] / CDIM;

    prepA_kernel<<<H * NCH, 256, 0, stream>>>(Ws, as_, ws);
    prepB_kernel<<<H, 256, 0, stream>>>(pe, bs, as_, ws);
    score_kernel<<<NB, 256, 0, stream>>>(codes, ws, out, ws, n_codes);
    sreduce_kernel<<<1, 256, 0, stream>>>(ws);
    int tot4 = (H * n_codes) / 4;
    norm_kernel<<<(tot4 + 255) / 256, 256, 0, stream>>>(out, ws, n_codes);
}

// Round 5
// 88.620 us; speedup vs baseline: 1.3942x; 1.1105x over previous
//
#include <hip/hip_runtime.h>
#include <hip/hip_bf16.h>

#define H     4
#define HID   256
#define CDIM  512
#define NCH   32              // d-chunks in prepA
#define DPER  (HID / NCH)     // 8 rows per chunk
#define NB    2048            // blocks in score pass

typedef float f32x4 __attribute__((ext_vector_type(4)));

// ws layout (float offsets)
#define WS_P1   0                        // H*NCH*CDIM  w1 partials
#define WS_P2   (WS_P1 + H * NCH * CDIM) // H*NCH*CDIM  w2 partials
#define WS_W2   (WS_P2 + H * NCH * CDIM) // H*CDIM
#define WS_PRE  (WS_W2 + H * CDIM)       // H
#define WS_BMS  (WS_PRE + H)             // H*NB*2 (max,sum interleaved)

// Pass A1: partial w1/w2 over d-chunks. 128 blocks, each reads 16KB contiguous.
__global__ void __launch_bounds__(256) prepA_kernel(
    const float* __restrict__ Ws, const float* __restrict__ as_,
    float* __restrict__ ws)
{
    int h = blockIdx.x >> 5, chunk = blockIdx.x & (NCH - 1);
    int t = threadIdx.x;
    const float* W  = Ws + ((size_t)h * HID + chunk * DPER) * CDIM;
    const float* a1 = as_ + (size_t)h * 2 * HID + chunk * DPER;
    const float* a2 = a1 + HID;
    int c0 = t, c1 = t + 256;
    float w1a = 0.f, w1b = 0.f, w2a = 0.f, w2b = 0.f;
#pragma unroll
    for (int d = 0; d < DPER; ++d) {
        float x0 = W[d * CDIM + c0], x1 = W[d * CDIM + c1];
        float v1 = a1[d], v2 = a2[d];
        w1a = fmaf(v1, x0, w1a); w2a = fmaf(v2, x0, w2a);
        w1b = fmaf(v1, x1, w1b); w2b = fmaf(v2, x1, w2b);
    }
    size_t base = (size_t)(h * NCH + chunk) * CDIM;
    ws[WS_P1 + base + c0] = w1a; ws[WS_P1 + base + c1] = w1b;
    ws[WS_P2 + base + c0] = w2a; ws[WS_P2 + base + c1] = w2b;
}

// Pass A2: reduce chunk partials -> w2[h,c]; pre[h] = pe.w1 + bs.(a1+a2)
__global__ void __launch_bounds__(256) prepB_kernel(
    const float* __restrict__ pe, const float* __restrict__ bs,
    const float* __restrict__ as_, float* __restrict__ ws)
{
    int h = blockIdx.x;
    int t = threadIdx.x;
    int c0 = t, c1 = t + 256;
    float w1a = 0.f, w1b = 0.f, w2a = 0.f, w2b = 0.f;
#pragma unroll
    for (int k = 0; k < NCH; ++k) {
        size_t base = (size_t)(h * NCH + k) * CDIM;
        w1a += ws[WS_P1 + base + c0]; w1b += ws[WS_P1 + base + c1];
        w2a += ws[WS_P2 + base + c0]; w2b += ws[WS_P2 + base + c1];
    }
    ws[WS_W2 + h * CDIM + c0] = w2a;
    ws[WS_W2 + h * CDIM + c1] = w2b;
    const float* a1 = as_ + (size_t)h * 2 * HID;
    const float* a2 = a1 + HID;
    float contrib = w1a * pe[c0] + w1b * pe[c1];
    contrib += bs[h * HID + t] * (a1[t] + a2[t]);
    __shared__ float red[256];
    red[t] = contrib;
    __syncthreads();
    for (int s2 = 128; s2 > 0; s2 >>= 1) {
        if (t < s2) red[t] += red[t + s2];
        __syncthreads();
    }
    if (t == 0) ws[WS_PRE + h] = red[0];
}

__device__ __forceinline__ void load_quad(const float* __restrict__ codes,
                                          long long q, int lane, f32x4 v[8])
{
    const f32x4* R = (const f32x4*)codes + ((size_t)q << 9);
#pragma unroll
    for (int r = 0; r < 4; ++r) {
        v[2 * r]     = __builtin_nontemporal_load(R + r * 128 + lane);
        v[2 * r + 1] = __builtin_nontemporal_load(R + r * 128 + 64 + lane);
    }
}

__device__ __forceinline__ void online_merge(float& m, float& s, float m2, float s2)
{
    float mm = fmaxf(m, m2);
    s = s * __expf(m - mm) + s2 * __expf(m2 - mm);
    m = mm;
}

// reduce 4 rows x 4 heads; lane ends with e for (head=lane&3, row=(lane>>2)&3)
__device__ __forceinline__ void compute_quad(
    const f32x4 v[8], const f32x4 w2a[H], const f32x4 w2b[H],
    float mypre, int lane, int hsel, bool b0, bool b1, bool b2, bool b3,
    long long q, int n_codes, float* __restrict__ e_out, float& m, float& s)
{
    float A[4][H];
#pragma unroll
    for (int r = 0; r < 4; ++r)
#pragma unroll
        for (int h = 0; h < H; ++h) {
            A[r][h] = v[2*r].x * w2a[h].x + v[2*r].y * w2a[h].y +
                      v[2*r].z * w2a[h].z + v[2*r].w * w2a[h].w +
                      v[2*r+1].x * w2b[h].x + v[2*r+1].y * w2b[h].y +
                      v[2*r+1].z * w2b[h].z + v[2*r+1].w * w2b[h].w;
        }
#pragma unroll
    for (int r = 0; r < 4; ++r)
#pragma unroll
        for (int h = 0; h < H; ++h) {
            A[r][h] += __shfl_xor(A[r][h], 1, 64);
            A[r][h] += __shfl_xor(A[r][h], 2, 64);
        }
    float B[4];
#pragma unroll
    for (int r = 0; r < 4; ++r) {
        float t01 = b0 ? A[r][1] : A[r][0];
        float t23 = b0 ? A[r][3] : A[r][2];
        B[r] = b1 ? t23 : t01;
        B[r] += __shfl_xor(B[r], 4, 64);
    }
    float C0 = b2 ? B[1] : B[0];
    float C1 = b2 ? B[3] : B[2];
    C0 += __shfl_xor(C0, 8, 64);
    C1 += __shfl_xor(C1, 8, 64);
    float z = b3 ? C1 : C0;
    z += __shfl_xor(z, 16, 64);
    z += __shfl_xor(z, 32, 64);

    float e = mypre + z;
    e = e >= 0.f ? e : 0.2f * e;
    float mm = fmaxf(m, e);
    s = s * __expf(m - mm) + __expf(e - mm);
    m = mm;
    if (!(lane & 48)) {
        int rowslot = (lane >> 2) & 3;
        e_out[(size_t)hsel * n_codes + ((size_t)q << 2) + rowslot] = e;
    }
}

// Pass B: wave processes 4 rows/iter with register ping-pong prefetch.
__global__ void __launch_bounds__(256) score_kernel(
    const float* __restrict__ codes, const float* __restrict__ ws_in,
    float* __restrict__ e_out, float* __restrict__ ws_out, int n_codes)
{
    const int lane = threadIdx.x & 63;
    const int wid  = threadIdx.x >> 6;
    const int gw   = blockIdx.x * 4 + wid;
    const long long Wtot = (long long)gridDim.x * 4;

    f32x4 w2a[H], w2b[H];
#pragma unroll
    for (int h = 0; h < H; ++h) {
        w2a[h] = *(const f32x4*)&ws_in[WS_W2 + h * CDIM + 4 * lane];
        w2b[h] = *(const f32x4*)&ws_in[WS_W2 + h * CDIM + 256 + 4 * lane];
    }
    const int  hsel = lane & 3;
    const bool b0 = lane & 1, b1 = lane & 2, b2 = lane & 4, b3 = lane & 8;
    const float mypre = ws_in[WS_PRE + hsel];

    const long long nquads = (long long)n_codes >> 2;
    const long long qs = (long long)gw * nquads / Wtot;
    const long long qe = ((long long)gw + 1) * nquads / Wtot;

    float m = -1e30f, s = 0.f;

    f32x4 P[8], Q[8];
    long long q = qs;
    if (q < qe) load_quad(codes, q, lane, P);
    while (q + 2 <= qe) {
        load_quad(codes, q + 1, lane, Q);
        compute_quad(P, w2a, w2b, mypre, lane, hsel, b0, b1, b2, b3,
                     q, n_codes, e_out, m, s);
        if (q + 2 < qe) load_quad(codes, q + 2, lane, P);
        compute_quad(Q, w2a, w2b, mypre, lane, hsel, b0, b1, b2, b3,
                     q + 1, n_codes, e_out, m, s);
        q += 2;
    }
    if (q < qe)
        compute_quad(P, w2a, w2b, mypre, lane, hsel, b0, b1, b2, b3,
                     q, n_codes, e_out, m, s);

    // row tail (n_codes % 4), handled by last wave; zero for n=200000
    if (gw == Wtot - 1) {
        for (int n0 = (int)(nquads << 2); n0 < n_codes; ++n0) {
            const f32x4* R = (const f32x4*)codes + (size_t)n0 * 128;
            f32x4 xa = __builtin_nontemporal_load(R + lane);
            f32x4 xb = __builtin_nontemporal_load(R + 64 + lane);
            float A[H];
#pragma unroll
            for (int h = 0; h < H; ++h) {
                A[h] = xa.x * w2a[h].x + xa.y * w2a[h].y +
                       xa.z * w2a[h].z + xa.w * w2a[h].w +
                       xb.x * w2b[h].x + xb.y * w2b[h].y +
                       xb.z * w2b[h].z + xb.w * w2b[h].w;
                A[h] += __shfl_xor(A[h], 1, 64);
                A[h] += __shfl_xor(A[h], 2, 64);
            }
            float t01 = b0 ? A[1] : A[0], t23 = b0 ? A[3] : A[2];
            float v = b1 ? t23 : t01;
#pragma unroll
            for (int msk = 4; msk <= 32; msk <<= 1) v += __shfl_xor(v, msk, 64);
            float e = mypre + v;
            e = e >= 0.f ? e : 0.2f * e;
            if (!(lane & 12)) {   // exactly one rowslot group absorbs it
                float mm = fmaxf(m, e);
                s = s * __expf(m - mm) + __expf(e - mm);
                m = mm;
            }
            if (lane < H) e_out[(size_t)hsel * n_codes + n0] = e;
        }
    }

    // merge rowslot replicas (bits 2,3); bits 4,5 are identical copies
    {
        float M2 = __shfl_xor(m, 4, 64), S2 = __shfl_xor(s, 4, 64);
        online_merge(m, s, M2, S2);
        M2 = __shfl_xor(m, 8, 64); S2 = __shfl_xor(s, 8, 64);
        online_merge(m, s, M2, S2);
    }

    __shared__ float lm[4][H], ls[4][H];
    if (lane < H) { lm[wid][lane] = m; ls[wid][lane] = s; }
    __syncthreads();
    if (threadIdx.x < H) {
        int h = threadIdx.x;
        float M = -1e30f, S = 0.f;
#pragma unroll
        for (int w = 0; w < 4; ++w) online_merge(M, S, lm[w][h], ls[w][h]);
        float2 v = make_float2(M, S);
        *(float2*)&ws_out[WS_BMS + (size_t)(h * NB + blockIdx.x) * 2] = v;
    }
}

// Pass C: per-block redundant reduce of this head's NB partials, then normalize.
__global__ void __launch_bounds__(256) norm_kernel(
    float* __restrict__ e, const float* __restrict__ ws, int n_codes)
{
    const int h    = blockIdx.y;
    const int lane = threadIdx.x & 63;
    const int wid  = threadIdx.x >> 6;

    float M = -1e30f, S = 0.f;
    const float* Pp = &ws[WS_BMS + (size_t)h * NB * 2];
    for (int i = threadIdx.x; i < NB; i += 256) {
        float2 v = *(const float2*)&Pp[2 * i];
        online_merge(M, S, v.x, v.y);
    }
#pragma unroll
    for (int msk = 1; msk < 64; msk <<= 1) {
        float M2 = __shfl_xor(M, msk, 64), S2 = __shfl_xor(S, msk, 64);
        online_merge(M, S, M2, S2);
    }
    __shared__ float sm[4], ss[4];
    if (lane == 0) { sm[wid] = M; ss[wid] = S; }
    __syncthreads();
    float gm = -1e30f, gs = 0.f;
#pragma unroll
    for (int w = 0; w < 4; ++w) online_merge(gm, gs, sm[w], ss[w]);
    float gi = 1.f / gs;

    int perh4 = n_codes >> 2;
    int idx = blockIdx.x * 256 + threadIdx.x;
    if (idx < perh4) {
        float4* ep = (float4*)(e + (size_t)h * n_codes) + idx;
        float4 v = *ep;
        v.x = __expf(v.x - gm) * gi;
        v.y = __expf(v.y - gm) * gi;
        v.z = __expf(v.z - gm) * gi;
        v.w = __expf(v.w - gm) * gi;
        *ep = v;
    }
    // scalar tail (n_codes % 4) — empty for n=200000
    if (blockIdx.x == 0 && threadIdx.x < (n_codes & 3)) {
        int n0 = (perh4 << 2) + threadIdx.x;
        float x = e[(size_t)h * n_codes + n0];
        e[(size_t)h * n_codes + n0] = __expf(x - gm) * gi;
    }
}

extern "C" void kernel_launch(void* const* d_in, const int* in_sizes, int n_in,
                              void* d_out, int out_size, void* d_ws, size_t ws_size,
                              hipStream_t stream)
{
    const float* pe    = (const float*)d_in[0];   // (1,512)
    const float* codes = (const float*)d_in[1];   // (n,512)
    const float* Ws    = (const float*)d_in[2];   // (4,256,512)
    const float* bs    = (const float*)d_in[3];   // (4,256)
    const float* as_   = (const float*)d_in[4];   // (4,512)
    float* out = (float*)d_out;                   // (4,n)
    float* ws  = (float*)d_ws;
    int n_codes = in_sizes[1] / CDIM;

    prepA_kernel<<<H * NCH, 256, 0, stream>>>(Ws, as_, ws);
    prepB_kernel<<<H, 256, 0, stream>>>(pe, bs, as_, ws);
    score_kernel<<<NB, 256, 0, stream>>>(codes, ws, out, ws, n_codes);
    int perh4 = n_codes >> 2;
    dim3 ngrid((perh4 + 255) / 256, H);
    norm_kernel<<<ngrid, 256, 0, stream>>>(out, ws, n_codes);
}